// Round 20
// baseline (96.767 us; speedup 1.0000x reference)
//
#include <hip/hip_runtime.h>
#include <cmath>

typedef float f4 __attribute__((ext_vector_type(4)));
typedef float f32x4 __attribute__((ext_vector_type(4)));
typedef short bf16x8 __attribute__((ext_vector_type(8)));
typedef unsigned short u16x8 __attribute__((ext_vector_type(8)));
typedef unsigned int u32x4 __attribute__((ext_vector_type(4)));

#define SCALEF 8.0f   // alpha/rank = 32/4

// lgkm-only barrier: global prefetches stay in flight across it
#define LDS_BAR() do { asm volatile("s_waitcnt lgkmcnt(0)" ::: "memory"); \
                       __builtin_amdgcn_s_barrier(); } while (0)

__device__ __forceinline__ unsigned cvtpk(float lo, float hi) {
    unsigned r;
    asm("v_cvt_pk_bf16_f32 %0, %1, %2" : "=v"(r) : "v"(lo), "v"(hi));
    return r;
}
__device__ __forceinline__ bf16x8 packA(const f4 a, const f4 b) {
    u32x4 u;
    u[0] = cvtpk(a[0], a[1]);
    u[1] = cvtpk(a[2], a[3]);
    u[2] = cvtpk(b[0], b[1]);
    u[3] = cvtpk(b[2], b[3]);
    return __builtin_bit_cast(bf16x8, u);
}

// ---- k0: prepack 12 weight rows into MFMA B-fragment stream (bf16) -------
// entry idx = s*64 + l: 8 bf16 = W[l&15][32s + (l>>4)*8 + j], 0-pad w>=12.
__global__ __launch_bounds__(256, 4) void k0_pack(
    const float* __restrict__ A_w,
    const float* __restrict__ router_w,
    unsigned short* __restrict__ wq)
{
    const int idx = blockIdx.x * 256 + threadIdx.x;   // 0..8191
    const int l = idx & 63, s = idx >> 6;
    const int w = l & 15;
    const int kb = 32 * s + (l >> 4) * 8;
    u16x8 o = (u16x8)0;
    if (w < 12) {
        const float* __restrict__ row = (w < 8)
            ? router_w + (size_t)w * 4096
            : A_w + (size_t)(w - 8) * 4096;
#pragma unroll
        for (int j = 0; j < 8; ++j) {
            union { float f; unsigned u; } a;
            a.f = row[kb + j];
            o[j] = (unsigned short)((a.u + 0x7FFFu + ((a.u >> 16) & 1u)) >> 16);
        }
    }
    *((u16x8*)wq + idx) = o;
}

struct Banks { f4 a0[4], a1[4]; u16x8 wb[4]; };
__device__ __forceinline__ void load4(Banks& B, const f4* __restrict__ xr,
                                      const u16x8* __restrict__ wr, int sb) {
#pragma unroll
    for (int i = 0; i < 4; ++i) {
        B.a0[i] = xr[8 * (sb + i)];
        B.a1[i] = xr[8 * (sb + i) + 1];
        B.wb[i] = wr[(sb + i) << 6];
    }
}
__device__ __forceinline__ void mfma4(f32x4& acc, const Banks& B) {
#pragma unroll
    for (int i = 0; i < 4; ++i)
        acc = __builtin_amdgcn_mfma_f32_16x16x32_bf16(
            packA(B.a0[i], B.a1[i]), __builtin_bit_cast(bf16x8, B.wb[i]),
            acc, 0, 0, 0);
}

// ---- main: 512 blocks x 8 waves (512 thr); block = tiles {b, b+512};
// K split 8-way (16 steps/wave). 1 block/CU -> 2 waves/SIMD -> 256-VGPR
// budget: tile-1 bank prefetch survives the allocator (R13 fix). -----------
__global__ __launch_bounds__(512, 1) void tmlora_main(
    const float* __restrict__ x,
    const unsigned short* __restrict__ wq,
    const float* __restrict__ B_w,
    const float* __restrict__ expert_vectors,
    float* __restrict__ out)
{
    __shared__ float red[2][8][16][17];   // [buf][wave][token][weight]
    __shared__ f4    hsh[2][16];          // [buf][token], SCALEF folded

    const int tid  = threadIdx.x;        // 0..511
    const int wid  = tid >> 6, lane = tid & 63;
    const int tokA = blockIdx.x * 16;            // tile 0
    const int tokB = (blockIdx.x + 512) * 16;    // tile 1
    const int s0   = wid * 16;                   // wave's K-step base

    const f4* __restrict__ xrA =
        (const f4*)x + ((size_t)(tokA + (lane & 15)) << 10) + ((lane >> 4) << 1);
    const f4* __restrict__ xrB =
        (const f4*)x + ((size_t)(tokB + (lane & 15)) << 10) + ((lane >> 4) << 1);
    const u16x8* __restrict__ wr = (const u16x8*)wq + lane;

    // ---- B_w register cache FIRST (oldest vm ops): store-phase waits on
    // these never force the (younger) tile-1 prefetch to drain. 32 VGPR. ----
    const f4* __restrict__ b4 = (const f4*)B_w;
    f4 Bc[2][4];
#pragma unroll
    for (int j = 0; j < 2; ++j)
#pragma unroll
        for (int m = 0; m < 4; ++m)
            Bc[j][m] = b4[4 * (tid + 512 * j) + m];

    Banks A, C;
    load4(A, xrA, wr, s0);
    load4(C, xrA, wr, s0 + 4);

    // ================= tile 0 K-loop (16 steps), tail prefetches tile 1 ====
    f32x4 acc = {0.f, 0.f, 0.f, 0.f};
    mfma4(acc, A); load4(A, xrA, wr, s0 + 8);
    mfma4(acc, C); load4(C, xrA, wr, s0 + 12);
    mfma4(acc, A); load4(A, xrB, wr, s0);        // tile-1 prefetch
    mfma4(acc, C); load4(C, xrB, wr, s0 + 4);    // tile-1 prefetch
    __builtin_amdgcn_sched_barrier(0);           // pin: prefetch stays above

#define FINISH_TILE(BUF, TOK0)                                                 \
  {                                                                            \
    _Pragma("unroll")                                                          \
    for (int r = 0; r < 4; ++r)                                                \
      red[BUF][wid][(lane >> 4) * 4 + r][lane & 15] = acc[r];                  \
    LDS_BAR();                                                                 \
    if (tid < 16) {                                                            \
      float s12[12];                                                           \
      _Pragma("unroll")                                                        \
      for (int w = 0; w < 12; ++w) {                                           \
        float s = red[BUF][0][tid][w];                                         \
        _Pragma("unroll")                                                      \
        for (int j = 1; j < 8; ++j) s += red[BUF][j][tid][w];                  \
        s12[w] = s;                                                            \
      }                                                                        \
      int   idx[4];                                                            \
      float val[4];                                                            \
      _Pragma("unroll")                                                        \
      for (int k = 0; k < 4; ++k) {                                            \
        int bi = 0; float bv = s12[0];                                         \
        _Pragma("unroll")                                                      \
        for (int e = 1; e < 8; ++e)                                            \
          if (s12[e] > bv) { bv = s12[e]; bi = e; }                            \
        idx[k] = bi; val[k] = bv;                                              \
        _Pragma("unroll")                                                      \
        for (int e = 0; e < 8; ++e)                                            \
          if (e == bi) s12[e] = -INFINITY;                                     \
      }                                                                        \
      float ex[4], se = 0.f;                                                   \
      _Pragma("unroll")                                                        \
      for (int k = 0; k < 4; ++k) { ex[k] = expf(val[k] - val[0]); se += ex[k]; } \
      const float inv = 1.f / se;                                              \
      float Et[4] = {0.f, 0.f, 0.f, 0.f};                                      \
      _Pragma("unroll")                                                        \
      for (int k = 0; k < 4; ++k) {                                            \
        const float wgt = ex[k] * inv;                                         \
        _Pragma("unroll")                                                      \
        for (int r = 0; r < 4; ++r)                                            \
          Et[r] = fmaf(wgt, expert_vectors[idx[k] * 4 + r], Et[r]);            \
      }                                                                        \
      f4 hv4;                                                                  \
      _Pragma("unroll")                                                        \
      for (int r = 0; r < 4; ++r) {                                            \
        const float hv = s12[8 + r] + Et[r];                                   \
        hv4[r] = SCALEF * 0.5f * hv *                                          \
                 (1.f + erff(hv * 0.70710678118654752f));                      \
      }                                                                        \
      hsh[BUF][tid] = hv4;                                                     \
    }                                                                          \
    LDS_BAR();                                                                 \
    _Pragma("unroll")                                                          \
    for (int j = 0; j < 2; ++j) {                                              \
      const int c = tid + 512 * j;                                             \
      _Pragma("unroll")                                                        \
      for (int t = 0; t < 16; ++t) {                                           \
        const f4 hh = hsh[BUF][t];                                             \
        f4 v;                                                                  \
        v[0] = Bc[j][0][0]*hh[0] + Bc[j][0][1]*hh[1] + Bc[j][0][2]*hh[2] + Bc[j][0][3]*hh[3]; \
        v[1] = Bc[j][1][0]*hh[0] + Bc[j][1][1]*hh[1] + Bc[j][1][2]*hh[2] + Bc[j][1][3]*hh[3]; \
        v[2] = Bc[j][2][0]*hh[0] + Bc[j][2][1]*hh[1] + Bc[j][2][2]*hh[2] + Bc[j][2][3]*hh[3]; \
        v[3] = Bc[j][3][0]*hh[0] + Bc[j][3][1]*hh[1] + Bc[j][3][2]*hh[2] + Bc[j][3][3]*hh[3]; \
        __builtin_nontemporal_store(                                           \
            v, (f4*)out + (size_t)((TOK0) + t) * 1024 + c);                    \
      }                                                                        \
    }                                                                          \
  }

    FINISH_TILE(0, tokA)   // tile-1's 24 HBM loads fly under this

    // ================= tile 1 K-loop (16 steps) ============================
    acc = (f32x4){0.f, 0.f, 0.f, 0.f};
    mfma4(acc, A); load4(A, xrB, wr, s0 + 8);
    mfma4(acc, C); load4(C, xrB, wr, s0 + 12);
    mfma4(acc, A);
    mfma4(acc, C);

    FINISH_TILE(1, tokB)

#undef FINISH_TILE
}

extern "C" void kernel_launch(void* const* d_in, const int* in_sizes, int n_in,
                              void* d_out, int out_size, void* d_ws, size_t ws_size,
                              hipStream_t stream) {
    const float* x        = (const float*)d_in[0];
    const float* A_w      = (const float*)d_in[1];
    const float* B_w      = (const float*)d_in[2];
    const float* router_w = (const float*)d_in[3];
    const float* ev       = (const float*)d_in[4];
    float* out            = (float*)d_out;
    unsigned short* wq    = (unsigned short*)d_ws;   // 128 KB prepacked B-frags

    k0_pack<<<32, 256, 0, stream>>>(A_w, router_w, wq);
    tmlora_main<<<512, 512, 0, stream>>>(x, wq, B_w, ev, out);
}